// Round 1
// baseline (225.166 us; speedup 1.0000x reference)
//
#include <hip/hip_runtime.h>
#include <hip/hip_bf16.h>

typedef __bf16 bf16_t;
typedef __attribute__((ext_vector_type(8))) __bf16 bf16x8;
typedef __attribute__((ext_vector_type(4))) __bf16 bf16x4;
typedef __attribute__((ext_vector_type(4))) float f32x4;

#define NHEADS 32
#define HDIM 128
#define NKV 8
#define GQ 4
#define BATCH 8
#define SEQ 1024
#define QD (NHEADS * HDIM)   // 4096
#define KVD (NKV * HDIM)     // 1024
#define ATT_SCALE 0.08838834764831845f

#define QBLK 64
#define KBLK 64
#define NQT (SEQ / QBLK)     // 16
#define KPAD 136             // K_lds row stride (bf16) -> 272B, 2-way conflict free
#define VPAD 72              // Vt row stride -> 144B
#define PPAD 72              // P row stride -> 144B

// Block: 512 threads = 8 waves. Wave w -> query head g = w>>1 (within kv group),
// row half rh = (w&1)*32 (two 16-row MFMA fragments).
// All 4 GQA heads share the staged K/V tile (4x less K/V traffic).
__global__ __launch_bounds__(512, 2)
void attn_fwd_kernel(const float* __restrict__ qg, const float* __restrict__ kg,
                     const float* __restrict__ vg, float* __restrict__ og)
{
    __shared__ bf16_t Kl[KBLK * KPAD];       // 17408 B, row-major [kcol][d]
    __shared__ bf16_t Vt[HDIM * VPAD];       // 18432 B, transposed [d][kcol], 8-blk XOR swizzle
    __shared__ bf16_t Pl[8 * 16 * PPAD];     // 18432 B, per-wave P tile [16][PPAD]

    const int tid  = threadIdx.x;
    const int w    = tid >> 6;
    const int lane = tid & 63;
    const int l4   = lane >> 4;   // 0..3
    const int l16  = lane & 15;   // 0..15

    const int bid = blockIdx.x;
    const int nbh = BATCH * NKV;                 // 64
    const int bh  = bid % nbh;
    const int qt  = (NQT - 1) - bid / nbh;       // heaviest q-tiles dispatch first
    const int b   = bh / NKV;
    const int hk  = bh % NKV;
    const int g   = w >> 1;
    const int h   = hk * GQ + g;
    const int rh  = (w & 1) * 32;

    const long qtok0 = (long)b * SEQ + qt * QBLK;

    // ---- Q fragments in registers: 2 frags x 4 k-slices, A-layout row=l16, slot k=l4*8+e ----
    bf16x8 aq[2][4];
    #pragma unroll
    for (int f = 0; f < 2; ++f) {
        const float* qp = qg + (qtok0 + rh + f * 16 + l16) * QD + h * HDIM + l4 * 8;
        #pragma unroll
        for (int s = 0; s < 4; ++s) {
            float4 x = *(const float4*)(qp + s * 32);
            float4 y = *(const float4*)(qp + s * 32 + 4);
            bf16x8 t;
            t[0] = (bf16_t)x.x; t[1] = (bf16_t)x.y; t[2] = (bf16_t)x.z; t[3] = (bf16_t)x.w;
            t[4] = (bf16_t)y.x; t[5] = (bf16_t)y.y; t[6] = (bf16_t)y.z; t[7] = (bf16_t)y.w;
            aq[f][s] = t;
        }
    }

    f32x4 accO[2][8];
    float mrun[2][4], lsum[2][4];
    #pragma unroll
    for (int f = 0; f < 2; ++f) {
        #pragma unroll
        for (int n = 0; n < 8; ++n) accO[f][n] = (f32x4){0.f, 0.f, 0.f, 0.f};
        #pragma unroll
        for (int j = 0; j < 4; ++j) { mrun[f][j] = -1e30f; lsum[f][j] = 0.f; }
    }

    const long ktok0 = (long)b * SEQ;
    const int nkt = qt + 1;

    for (int kt = 0; kt < nkt; ++kt) {
        __syncthreads();   // previous tile's LDS reads done before overwrite
        // ---- stage K (row-major) and V (transposed + swizzled) to LDS, fp32->bf16 ----
        const float* kp = kg + (ktok0 + kt * KBLK) * KVD + hk * HDIM;
        const float* vp = vg + (ktok0 + kt * KBLK) * KVD + hk * HDIM;
        #pragma unroll
        for (int it = 0; it < 4; ++it) {
            int idx = it * 512 + tid;      // 0..2047
            int row = idx >> 5;            // kcol 0..63
            int c4  = (idx & 31) * 4;      // d 0..124
            float4 kf = *(const float4*)(kp + (long)row * KVD + c4);
            bf16x4 k4;
            k4[0] = (bf16_t)kf.x; k4[1] = (bf16_t)kf.y; k4[2] = (bf16_t)kf.z; k4[3] = (bf16_t)kf.w;
            *(bf16x4*)(&Kl[row * KPAD + c4]) = k4;
            float4 vf = *(const float4*)(vp + (long)row * KVD + c4);
            const float* vfa = (const float*)&vf;
            #pragma unroll
            for (int m = 0; m < 4; ++m) {
                int d   = c4 + m;
                int blk = (row >> 3) ^ ((d >> 3) & 7);   // XOR swizzle on 8-elem kcol blocks
                Vt[d * VPAD + blk * 8 + (row & 7)] = (bf16_t)vfa[m];
            }
        }
        __syncthreads();

        const bool diag = (kt == qt);
        bf16_t* pw = &Pl[w * 16 * PPAD];

        #pragma unroll
        for (int f = 0; f < 2; ++f) {
            // ---- S = Q K^T : D[q=l4*4+j][kcol=n*16+l16] ----
            f32x4 accS[4];
            #pragma unroll
            for (int n = 0; n < 4; ++n) {
                f32x4 acc = (f32x4){0.f, 0.f, 0.f, 0.f};
                #pragma unroll
                for (int s = 0; s < 4; ++s) {
                    bf16x8 bk = *(const bf16x8*)(&Kl[(n * 16 + l16) * KPAD + s * 32 + l4 * 8]);
                    acc = __builtin_amdgcn_mfma_f32_16x16x32_bf16(aq[f][s], bk, acc, 0, 0, 0);
                }
                accS[n] = acc;
            }

            const int qrow_loc = rh + f * 16 + l4 * 4;   // + j
            float pm[4];
            #pragma unroll
            for (int j = 0; j < 4; ++j) pm[j] = -1e30f;
            #pragma unroll
            for (int n = 0; n < 4; ++n) {
                #pragma unroll
                for (int j = 0; j < 4; ++j) {
                    float sv = accS[n][j] * ATT_SCALE;
                    if (diag && (n * 16 + l16 > qrow_loc + j)) sv = -1e30f;
                    accS[n][j] = sv;
                    pm[j] = fmaxf(pm[j], sv);
                }
            }
            // row max across the 16 lanes holding this row
            #pragma unroll
            for (int j = 0; j < 4; ++j) {
                float m0 = pm[j];
                m0 = fmaxf(m0, __shfl_xor(m0, 1));
                m0 = fmaxf(m0, __shfl_xor(m0, 2));
                m0 = fmaxf(m0, __shfl_xor(m0, 4));
                m0 = fmaxf(m0, __shfl_xor(m0, 8));
                pm[j] = m0;
            }
            float al[4], rs[4];
            #pragma unroll
            for (int j = 0; j < 4; ++j) {
                float mnew = fmaxf(mrun[f][j], pm[j]);
                al[j] = __expf(mrun[f][j] - mnew);
                mrun[f][j] = mnew;
                rs[j] = 0.f;
            }
            #pragma unroll
            for (int n = 0; n < 4; ++n) {
                #pragma unroll
                for (int j = 0; j < 4; ++j) {
                    float p = __expf(accS[n][j] - mrun[f][j]);
                    accS[n][j] = p;
                    rs[j] += p;
                }
            }
            #pragma unroll
            for (int j = 0; j < 4; ++j) {
                float r = rs[j];
                r += __shfl_xor(r, 1);
                r += __shfl_xor(r, 2);
                r += __shfl_xor(r, 4);
                r += __shfl_xor(r, 8);
                lsum[f][j] = lsum[f][j] * al[j] + r;
            }
            // rescale O
            #pragma unroll
            for (int n = 0; n < 8; ++n) {
                #pragma unroll
                for (int j = 0; j < 4; ++j) accO[f][n][j] *= al[j];
            }
            // ---- P -> LDS (C/D layout -> A-fragment layout round trip) ----
            #pragma unroll
            for (int n = 0; n < 4; ++n) {
                #pragma unroll
                for (int j = 0; j < 4; ++j)
                    pw[(l4 * 4 + j) * PPAD + n * 16 + l16] = (bf16_t)accS[n][j];
            }
            asm volatile("s_waitcnt lgkmcnt(0)" ::: "memory");
            __builtin_amdgcn_sched_barrier(0);
            // ---- O += P V : A row=l16, slot kcol=ks*32+l4*8+e; B from transposed Vt ----
            #pragma unroll
            for (int ks = 0; ks < 2; ++ks) {
                bf16x8 ap = *(const bf16x8*)(&pw[l16 * PPAD + ks * 32 + l4 * 8]);
                #pragma unroll
                for (int n = 0; n < 8; ++n) {
                    int d   = n * 16 + l16;
                    int blk = (ks * 4 + l4) ^ ((d >> 3) & 7);
                    bf16x8 bv = *(const bf16x8*)(&Vt[d * VPAD + blk * 8]);
                    accO[f][n] = __builtin_amdgcn_mfma_f32_16x16x32_bf16(ap, bv, accO[f][n], 0, 0, 0);
                }
            }
        }
    }

    // ---- epilogue: normalize and store fp32 ----
    #pragma unroll
    for (int f = 0; f < 2; ++f) {
        #pragma unroll
        for (int j = 0; j < 4; ++j) {
            float inv = 1.f / lsum[f][j];
            float* op = og + (qtok0 + rh + f * 16 + l4 * 4 + j) * QD + h * HDIM;
            #pragma unroll
            for (int n = 0; n < 8; ++n)
                op[n * 16 + l16] = accO[f][n][j] * inv;
        }
    }
}

extern "C" void kernel_launch(void* const* d_in, const int* in_sizes, int n_in,
                              void* d_out, int out_size, void* d_ws, size_t ws_size,
                              hipStream_t stream) {
    const float* q = (const float*)d_in[0];
    const float* k = (const float*)d_in[1];
    const float* v = (const float*)d_in[2];
    float* o = (float*)d_out;
    dim3 grid(NQT * BATCH * NKV);   // 1024 blocks, heavy tiles first
    attn_fwd_kernel<<<grid, 512, 0, stream>>>(q, k, v, o);
}